// Round 10
// baseline (175.053 us; speedup 1.0000x reference)
//
#include <hip/hip_runtime.h>
#include <hip/hip_bf16.h>

#define NB 32
#define NS 4
#define NL 64
#define NC 32
#define NH 4
#define ND 8
#define NCP 16

using fp = const float* __restrict__;

// ---------------------------------------------------------------------------
// K1: block=(b,s), 256 threads = 4 waves. Wave w: QKV slice e in [8w,8w+8),
// attention head w, out-proj channels [8w,8w+8). Lane = bin-row l.
// LDS layouts are [e][l] (lane-stride-1 writes, broadcast reads): conflict-free.
// bulk tile padded to 65. xpost written TRANSPOSED: [b][s][c][l].
// (unchanged from R9)
// ---------------------------------------------------------------------------
__global__ __launch_bounds__(256) void k1_attn(
    fp ctcf, fp hac, fp me1, fp me3, fp bulk,
    fp we_w, fp we_b, fp pos, fp mn_g, fp mn_b,
    fp wq, fp bq, fp wk, fp bk, fp wv, fp bv,
    fp wo, fp bo, fp an_g, fp an_b,
    fp conv_w, fp conv_b, fp gate_w, fp gate_b,
    float* __restrict__ xpostT)
{
    __shared__ float ks_s[NC*NL];     // [e][l]
    __shared__ float vs_s[NC*NL];     // [e][l]
    __shared__ float ao_s[NC*NL];     // [e][l]
    __shared__ float bulk_s[NL*65];   // [l][m] padded
    __shared__ float red1[256], red2[256];

    const int t = threadIdx.x;
    const int w = t >> 6;     // wave == head == channel-slice
    const int l = t & 63;     // bin row
    const int b = blockIdx.x >> 2;
    const int s = blockIdx.x & 3;

    for (int idx = t; idx < NL*NL; idx += 256)
        bulk_s[(idx >> 6)*65 + (idx & 63)] = bulk[b*NL*NL + idx];

    fp sigp = (s == 0) ? ctcf : (s == 1) ? hac : (s == 2) ? me1 : me3;
    const float sig = sigp[b*NL + l];

    // ---- embed + LN ----
    float x[NC];
    float mean = 0.f;
#pragma unroll
    for (int c = 0; c < NC; c++){
        x[c] = sig * we_w[c] + we_b[c] + pos[l*NC + c];
        mean += x[c];
    }
    mean *= (1.f/NC);
    float var = 0.f;
#pragma unroll
    for (int c = 0; c < NC; c++){ float d = x[c] - mean; var += d*d; }
    var *= (1.f/NC);
    float inv = rsqrtf(var + 1e-5f);
#pragma unroll
    for (int c = 0; c < NC; c++) x[c] = (x[c] - mean)*inv*mn_g[c] + mn_b[c];

    // ---- QKV slice ----
    float q[ND];
#pragma unroll
    for (int e8 = 0; e8 < ND; e8++){
        int e = w*ND + e8;
        float aq = bq[e], ak = bk[e], av = bv[e];
#pragma unroll
        for (int c = 0; c < NC; c++){
            float xv = x[c];
            aq += xv * wq[e*NC + c];
            ak += xv * wk[e*NC + c];
            av += xv * wv[e*NC + c];
        }
        q[e8] = aq;
        ks_s[e*NL + l] = ak;
        vs_s[e*NL + l] = av;
    }
    __syncthreads();

    // ---- attention head w ----
    const float rs8 = 0.35355339059327373f;
    const float cw = conv_w[w], cb = conv_b[w];
    float srow[NL];
    float mx = -1e30f;
    for (int m = 0; m < NL; m++){
        float dot = 0.f;
#pragma unroll
        for (int d = 0; d < ND; d++)
            dot += q[d] * ks_s[(w*ND + d)*NL + m];
        float v = dot*rs8 + bulk_s[l*65 + m]*cw + cb;
        srow[m] = v;
        mx = fmaxf(mx, v);
    }
    float sm = 0.f;
    for (int m = 0; m < NL; m++){ srow[m] = __expf(srow[m] - mx); sm += srow[m]; }
    float is = 1.f / sm;
    float o[ND];
#pragma unroll
    for (int d = 0; d < ND; d++) o[d] = 0.f;
    for (int m = 0; m < NL; m++){
        float a = srow[m] * is;
#pragma unroll
        for (int d = 0; d < ND; d++)
            o[d] += a * vs_s[(w*ND + d)*NL + m];
    }
#pragma unroll
    for (int c8 = 0; c8 < ND; c8++){
        float g = gate_b[w*ND + c8];
#pragma unroll
        for (int d = 0; d < ND; d++) g += gate_w[(w*ND + c8)*ND + d] * o[d];
        ao_s[(w*ND + c8)*NL + l] = o[c8] * (1.f/(1.f + __expf(-g)));
    }
    __syncthreads();

    // ---- out-proj + residual + LN ----
    float p8[ND];
    float psum = 0.f, psq = 0.f;
#pragma unroll
    for (int c8 = 0; c8 < ND; c8++){
        int c = w*ND + c8;
        float a = bo[c];
#pragma unroll
        for (int e = 0; e < NC; e++) a += ao_s[e*NL + l] * wo[c*NC + e];
        float val = x[c] + a;
        p8[c8] = val; psum += val; psq += val*val;
    }
    red1[w*64 + l] = psum;
    red2[w*64 + l] = psq;
    __syncthreads();
    float sum = 0.f, ssq = 0.f;
#pragma unroll
    for (int ww = 0; ww < 4; ww++){ sum += red1[ww*64 + l]; ssq += red2[ww*64 + l]; }
    mean = sum * (1.f/NC);
    var  = ssq * (1.f/NC) - mean*mean;
    inv  = rsqrtf(var + 1e-5f);
#pragma unroll
    for (int c8 = 0; c8 < ND; c8++){
        int c = w*ND + c8;
        xpostT[((b*NS + s)*NC + c)*NL + l] = (p8[c8] - mean)*inv*an_g[c] + an_b[c];
    }
}

// ---------------------------------------------------------------------------
// K23 (fused pair stage, z never materialized): block=(b,it) -> 512 blocks,
// 256 threads. feat[i,j,p] = mhat_i^T W_p mhat_j computed as:
//   u[p][i'][d] = sum_c mh[c][i] * pp_w[p, c*32+d]     (8 KB LDS, block's 4 i)
//   feat[p]     = sum_d u[p][i'][d] * md[d]            (md = mhat[:,j] in regs)
// Same total FMA as the old k2+k3, minus the z HBM round-trip and a launch.
// Step A: every wave redundantly computes mhat for its lane j (coalesced,
// L1-shared); wave 0 also writes mh[c][j] to LDS for Step B's column reads.
// ---------------------------------------------------------------------------
__global__ __launch_bounds__(256) void k23_pair(
    const float* __restrict__ xpostT, fp pp_w,
    fp pp_b, fp ada_g, fp ada_b, fp ada_alpha,
    float* __restrict__ out)
{
    __shared__ float mh[NC*NL];       // [c][j]
    __shared__ float u[NCP*4*NC];     // [p][i'][d]

    const int b  = blockIdx.x >> 4;
    const int it = blockIdx.x & 15;
    const int t  = threadIdx.x;
    const int w  = t >> 6;
    const int j  = t & 63;

    // ---- Step A: mhat for lane j (all waves; wave 0 publishes to LDS) ----
    float md[NC];
    {
        float sq = 0.f;
#pragma unroll
        for (int c = 0; c < NC; c++){
            const float* xp = xpostT + (b*NS*NC + c)*NL + j;
            float v = xp[0];
            v = fmaxf(v, xp[NC*NL]);
            v = fmaxf(v, xp[2*NC*NL]);
            v = fmaxf(v, xp[3*NC*NL]);
            md[c] = v; sq += v*v;
        }
        float iv = 1.f / fmaxf(sqrtf(sq), 1e-3f);
#pragma unroll
        for (int c = 0; c < NC; c++) md[c] *= iv;
        if (w == 0){
#pragma unroll
            for (int c = 0; c < NC; c++) mh[c*NL + j] = md[c];
        }
    }
    __syncthreads();

    // ---- Step B: u[p][i'][d], 2048 entries, 8 per thread ----
    // idx = loop*256 + t; d = idx&31 (lane-contiguous -> coalesced pp_w),
    // i' = (idx>>5)&3, p = idx>>7 (wave-uniform).
#pragma unroll
    for (int loop = 0; loop < 8; loop++){
        int idx = loop*256 + t;
        int d  = idx & 31;
        int ip = (idx >> 5) & 3;
        int p  = idx >> 7;
        int i  = it*4 + ip;
        float acc = 0.f;
#pragma unroll
        for (int c = 0; c < NC; c++)
            acc += mh[c*NL + i] * pp_w[p*NC*NC + c*NC + d];
        u[idx] = acc;
    }
    __syncthreads();

    // ---- Step C: wave w owns i = it*4 + w; lane j ----
    float f[NCP];
#pragma unroll 1
    for (int p = 0; p < NCP; p++){
        float a = 0.f;
#pragma unroll
        for (int d = 0; d < NC; d++)
            a += u[p*4*NC + w*NC + d] * md[d];    // u: wave-uniform broadcast
        f[p] = a;
    }

    // ---- Step D: AdaNorm + SiLU + store ----
    const float alpha = ada_alpha[0];
    float fsum = 0.f, fsq = 0.f;
#pragma unroll
    for (int p = 0; p < NCP; p++){
        float v = f[p] + pp_b[p];
        f[p] = v; fsum += v; fsq += v*v;
    }
    float fmean = fsum * (1.f/NCP);
    float fvar  = fsq * (1.f/NCP) - fmean*fmean;
    float finv  = rsqrtf(fvar + 1e-5f);
    const int i = it*4 + w;
#pragma unroll
    for (int p = 0; p < NCP; p++){
        float v = f[p] + alpha * ((f[p] - fmean)*finv*ada_g[p] + ada_b[p]);
        out[((b*NCP + p)*NL + i)*NL + j] = v / (1.f + __expf(-v));
    }
}

extern "C" void kernel_launch(void* const* d_in, const int* in_sizes, int n_in,
                              void* d_out, int out_size, void* d_ws, size_t ws_size,
                              hipStream_t stream)
{
    float* xpostT = (float*)d_ws;                    // 32*4*32*64 = 262144 f32

    k1_attn<<<NB*NS, 256, 0, stream>>>(
        (fp)d_in[0], (fp)d_in[1], (fp)d_in[2], (fp)d_in[3], (fp)d_in[4],
        (fp)d_in[5], (fp)d_in[6], (fp)d_in[7], (fp)d_in[8], (fp)d_in[9],
        (fp)d_in[10], (fp)d_in[11], (fp)d_in[12], (fp)d_in[13], (fp)d_in[14], (fp)d_in[15],
        (fp)d_in[16], (fp)d_in[17], (fp)d_in[18], (fp)d_in[19],
        (fp)d_in[20], (fp)d_in[21], (fp)d_in[22], (fp)d_in[23], xpostT);

    k23_pair<<<NB*16, 256, 0, stream>>>(
        xpostT, (fp)d_in[24], (fp)d_in[25], (fp)d_in[26], (fp)d_in[27], (fp)d_in[28],
        (float*)d_out);
}

// Round 11
// 143.011 us; speedup vs baseline: 1.2241x; 1.2241x over previous
//
#include <hip/hip_runtime.h>
#include <hip/hip_bf16.h>

#define NB 32
#define NS 4
#define NL 64
#define NC 32
#define NH 4
#define ND 8
#define NCP 16

using fp = const float* __restrict__;

// ---------------------------------------------------------------------------
// K1: block=(b,s), 256 threads = 4 waves. (unchanged from R10 — awaiting its
// own counters next round)
// ---------------------------------------------------------------------------
__global__ __launch_bounds__(256) void k1_attn(
    fp ctcf, fp hac, fp me1, fp me3, fp bulk,
    fp we_w, fp we_b, fp pos, fp mn_g, fp mn_b,
    fp wq, fp bq, fp wk, fp bk, fp wv, fp bv,
    fp wo, fp bo, fp an_g, fp an_b,
    fp conv_w, fp conv_b, fp gate_w, fp gate_b,
    float* __restrict__ xpostT)
{
    __shared__ float ks_s[NC*NL];     // [e][l]
    __shared__ float vs_s[NC*NL];     // [e][l]
    __shared__ float ao_s[NC*NL];     // [e][l]
    __shared__ float bulk_s[NL*65];   // [l][m] padded
    __shared__ float red1[256], red2[256];

    const int t = threadIdx.x;
    const int w = t >> 6;
    const int l = t & 63;
    const int b = blockIdx.x >> 2;
    const int s = blockIdx.x & 3;

    for (int idx = t; idx < NL*NL; idx += 256)
        bulk_s[(idx >> 6)*65 + (idx & 63)] = bulk[b*NL*NL + idx];

    fp sigp = (s == 0) ? ctcf : (s == 1) ? hac : (s == 2) ? me1 : me3;
    const float sig = sigp[b*NL + l];

    float x[NC];
    float mean = 0.f;
#pragma unroll
    for (int c = 0; c < NC; c++){
        x[c] = sig * we_w[c] + we_b[c] + pos[l*NC + c];
        mean += x[c];
    }
    mean *= (1.f/NC);
    float var = 0.f;
#pragma unroll
    for (int c = 0; c < NC; c++){ float d = x[c] - mean; var += d*d; }
    var *= (1.f/NC);
    float inv = rsqrtf(var + 1e-5f);
#pragma unroll
    for (int c = 0; c < NC; c++) x[c] = (x[c] - mean)*inv*mn_g[c] + mn_b[c];

    float q[ND];
#pragma unroll
    for (int e8 = 0; e8 < ND; e8++){
        int e = w*ND + e8;
        float aq = bq[e], ak = bk[e], av = bv[e];
#pragma unroll
        for (int c = 0; c < NC; c++){
            float xv = x[c];
            aq += xv * wq[e*NC + c];
            ak += xv * wk[e*NC + c];
            av += xv * wv[e*NC + c];
        }
        q[e8] = aq;
        ks_s[e*NL + l] = ak;
        vs_s[e*NL + l] = av;
    }
    __syncthreads();

    const float rs8 = 0.35355339059327373f;
    const float cw = conv_w[w], cb = conv_b[w];
    float srow[NL];
    float mx = -1e30f;
    for (int m = 0; m < NL; m++){
        float dot = 0.f;
#pragma unroll
        for (int d = 0; d < ND; d++)
            dot += q[d] * ks_s[(w*ND + d)*NL + m];
        float v = dot*rs8 + bulk_s[l*65 + m]*cw + cb;
        srow[m] = v;
        mx = fmaxf(mx, v);
    }
    float sm = 0.f;
    for (int m = 0; m < NL; m++){ srow[m] = __expf(srow[m] - mx); sm += srow[m]; }
    float is = 1.f / sm;
    float o[ND];
#pragma unroll
    for (int d = 0; d < ND; d++) o[d] = 0.f;
    for (int m = 0; m < NL; m++){
        float a = srow[m] * is;
#pragma unroll
        for (int d = 0; d < ND; d++)
            o[d] += a * vs_s[(w*ND + d)*NL + m];
    }
#pragma unroll
    for (int c8 = 0; c8 < ND; c8++){
        float g = gate_b[w*ND + c8];
#pragma unroll
        for (int d = 0; d < ND; d++) g += gate_w[(w*ND + c8)*ND + d] * o[d];
        ao_s[(w*ND + c8)*NL + l] = o[c8] * (1.f/(1.f + __expf(-g)));
    }
    __syncthreads();

    float p8[ND];
    float psum = 0.f, psq = 0.f;
#pragma unroll
    for (int c8 = 0; c8 < ND; c8++){
        int c = w*ND + c8;
        float a = bo[c];
#pragma unroll
        for (int e = 0; e < NC; e++) a += ao_s[e*NL + l] * wo[c*NC + e];
        float val = x[c] + a;
        p8[c8] = val; psum += val; psq += val*val;
    }
    red1[w*64 + l] = psum;
    red2[w*64 + l] = psq;
    __syncthreads();
    float sum = 0.f, ssq = 0.f;
#pragma unroll
    for (int ww = 0; ww < 4; ww++){ sum += red1[ww*64 + l]; ssq += red2[ww*64 + l]; }
    mean = sum * (1.f/NC);
    var  = ssq * (1.f/NC) - mean*mean;
    inv  = rsqrtf(var + 1e-5f);
#pragma unroll
    for (int c8 = 0; c8 < ND; c8++){
        int c = w*ND + c8;
        xpostT[((b*NS + s)*NC + c)*NL + l] = (p8[c8] - mean)*inv*an_g[c] + an_b[c];
    }
}

// ---------------------------------------------------------------------------
// K23 v2: block=(b,it) -> 512 blocks, 256 threads, 48 KB LDS (2 blocks/CU).
// All global reads cooperative/coalesced; pp_w staged to LDS in two 32 KB
// passes; mhat computed block-cooperatively (32 loads/thread, no redundancy).
//   mh[c][j]   : normalized mhat, LDS [c*64+j]
//   ppws       : 8 p-rows of pp_w per pass, LDS [pl*1024 + c*32 + d]
//   u[p][i'][d]: LDS [p*128 + ip*32 + d]   (invn borrows u[0..63] early)
// feat[p] = sum_d u[p][w][d] * md[d]; AdaNorm; SiLU; coalesced f32 stores.
// ---------------------------------------------------------------------------
__global__ __launch_bounds__(256) void k23_pair(
    const float* __restrict__ xpostT, fp pp_w,
    fp pp_b, fp ada_g, fp ada_b, fp ada_alpha,
    float* __restrict__ out)
{
    __shared__ float ppws[8*NC*NC];   // 8192 floats, 32 KB (per pass)
    __shared__ float mh[NC*NL];       // 2048 floats
    __shared__ float u[NCP*4*NC];     // 2048 floats ([0..63] = invn early)

    const int b  = blockIdx.x >> 4;
    const int it = blockIdx.x & 15;
    const int t  = threadIdx.x;
    const int w  = t >> 6;
    const int j  = t & 63;

    // ---- A1: cooperative mhat-raw: mh[cj] = max_s xpostT[b][s][cj] ----
    const float* xb = xpostT + b*NS*NC*NL;
#pragma unroll
    for (int k = 0; k < 8; k++){
        int cj = k*256 + t;                      // coalesced over lanes
        float v = xb[cj];
        v = fmaxf(v, xb[NC*NL + cj]);
        v = fmaxf(v, xb[2*NC*NL + cj]);
        v = fmaxf(v, xb[3*NC*NL + cj]);
        mh[cj] = v;
    }
    __syncthreads();

    // ---- A2: per-j inverse norms (t<64) + stage pp_w pass 0 ----
    if (t < NL){
        float sq = 0.f;
#pragma unroll
        for (int c = 0; c < NC; c++){ float v = mh[c*NL + t]; sq += v*v; }
        u[t] = 1.f / fmaxf(sqrtf(sq), 1e-3f);    // invn[j]
    }
    {   // pp_w rows p=0..7 -> ppws (independent of mh/invn)
        const float4* src = (const float4*)(pp_w);
        float4* dst = (float4*)ppws;
#pragma unroll
        for (int k = 0; k < 8; k++) dst[k*256 + t] = src[k*256 + t];
    }
    __syncthreads();

    // ---- A3: normalize mh in place ----
#pragma unroll
    for (int k = 0; k < 8; k++){
        int cj = k*256 + t;
        mh[cj] *= u[cj & 63];
    }
    __syncthreads();

    // ---- md registers (this lane's mhat column j) ----
    float md[NC];
#pragma unroll
    for (int c = 0; c < NC; c++) md[c] = mh[c*NL + j];

    // ---- B pass 0: u for p in [0,8) ----
#pragma unroll
    for (int loop = 0; loop < 4; loop++){
        int idx = loop*256 + t;                  // 0..1023
        int d  = idx & 31;
        int ip = (idx >> 5) & 3;
        int pl = idx >> 7;                       // 0..7
        int i  = it*4 + ip;
        float acc = 0.f;
#pragma unroll
        for (int c = 0; c < NC; c++)
            acc += mh[c*NL + i] * ppws[pl*1024 + c*32 + d];
        u[pl*128 + ip*32 + d] = acc;
    }
    __syncthreads();

    // ---- stage pp_w pass 1 (p=8..15) ----
    {
        const float4* src = (const float4*)(pp_w + 8*NC*NC);
        float4* dst = (float4*)ppws;
#pragma unroll
        for (int k = 0; k < 8; k++) dst[k*256 + t] = src[k*256 + t];
    }
    __syncthreads();

    // ---- B pass 1: u for p in [8,16) ----
#pragma unroll
    for (int loop = 0; loop < 4; loop++){
        int idx = loop*256 + t;
        int d  = idx & 31;
        int ip = (idx >> 5) & 3;
        int pl = idx >> 7;
        int i  = it*4 + ip;
        float acc = 0.f;
#pragma unroll
        for (int c = 0; c < NC; c++)
            acc += mh[c*NL + i] * ppws[pl*1024 + c*32 + d];
        u[(8 + pl)*128 + ip*32 + d] = acc;
    }
    __syncthreads();

    // ---- C: wave w owns i = it*4 + w; lane j ----
    float f[NCP];
#pragma unroll 1
    for (int p = 0; p < NCP; p++){
        float a = 0.f;
#pragma unroll
        for (int d = 0; d < NC; d++)
            a += u[p*128 + w*32 + d] * md[d];    // u consecutive -> b128 fuse
        f[p] = a;
    }

    // ---- D: AdaNorm + SiLU + store ----
    const float alpha = ada_alpha[0];
    float fsum = 0.f, fsq = 0.f;
#pragma unroll
    for (int p = 0; p < NCP; p++){
        float v = f[p] + pp_b[p];
        f[p] = v; fsum += v; fsq += v*v;
    }
    float fmean = fsum * (1.f/NCP);
    float fvar  = fsq * (1.f/NCP) - fmean*fmean;
    float finv  = rsqrtf(fvar + 1e-5f);
    const int i = it*4 + w;
#pragma unroll
    for (int p = 0; p < NCP; p++){
        float v = f[p] + alpha * ((f[p] - fmean)*finv*ada_g[p] + ada_b[p]);
        out[((b*NCP + p)*NL + i)*NL + j] = v / (1.f + __expf(-v));
    }
}

extern "C" void kernel_launch(void* const* d_in, const int* in_sizes, int n_in,
                              void* d_out, int out_size, void* d_ws, size_t ws_size,
                              hipStream_t stream)
{
    float* xpostT = (float*)d_ws;                    // 32*4*32*64 = 262144 f32

    k1_attn<<<NB*NS, 256, 0, stream>>>(
        (fp)d_in[0], (fp)d_in[1], (fp)d_in[2], (fp)d_in[3], (fp)d_in[4],
        (fp)d_in[5], (fp)d_in[6], (fp)d_in[7], (fp)d_in[8], (fp)d_in[9],
        (fp)d_in[10], (fp)d_in[11], (fp)d_in[12], (fp)d_in[13], (fp)d_in[14], (fp)d_in[15],
        (fp)d_in[16], (fp)d_in[17], (fp)d_in[18], (fp)d_in[19],
        (fp)d_in[20], (fp)d_in[21], (fp)d_in[22], (fp)d_in[23], xpostT);

    k23_pair<<<NB*16, 256, 0, stream>>>(
        xpostT, (fp)d_in[24], (fp)d_in[25], (fp)d_in[26], (fp)d_in[27], (fp)d_in[28],
        (float*)d_out);
}

// Round 12
// 142.316 us; speedup vs baseline: 1.2300x; 1.0049x over previous
//
#include <hip/hip_runtime.h>
#include <hip/hip_bf16.h>

#define NB 32
#define NS 4
#define NL 64
#define NC 32
#define NH 4
#define ND 8
#define NCP 16

using fp = const float* __restrict__;

// ---------------------------------------------------------------------------
// K1 v3: block=(b,s,half) -> 256 blocks (all CUs busy), 256 threads = 4 waves.
// Phase 1 (t = w*64+l): embed+LN row l; Q/K/V slice e in [8w,8w+8) -> LDS
//   qs/ks/vs [e][l]; x slice -> xs [e][l]. (full 64 rows; duplicated per half)
// Phase 2: wave w = head w; 2 lanes per row: r = half*32 + (lane>>1),
//   m-range = (lane&1)*32 .. +32. Score/softmax/PV chains halved; pair
//   combine via __shfl_xor(.,1). Gate: 4 channels per lane -> ao [e][r].
// Phase 3: out-proj 4 channels/thread (r = t&31, cg = t>>5), LN via LDS
//   reduce over the 8 channel-groups; write xpostT [b][s][c][l] coalesced.
// All LDS access patterns broadcast / 2-way (free). 4 barriers.
// ---------------------------------------------------------------------------
__global__ __launch_bounds__(256) void k1_attn(
    fp ctcf, fp hac, fp me1, fp me3, fp bulk,
    fp we_w, fp we_b, fp pos, fp mn_g, fp mn_b,
    fp wq, fp bq, fp wk, fp bk, fp wv, fp bv,
    fp wo, fp bo, fp an_g, fp an_b,
    fp conv_w, fp conv_b, fp gate_w, fp gate_b,
    float* __restrict__ xpostT)
{
    __shared__ float qs_s[NC*NL];      // [e][l]
    __shared__ float ks_s[NC*NL];      // [e][l]
    __shared__ float vs_s[NC*NL];      // [e][l]
    __shared__ float xs_s[NC*NL];      // [e][l]
    __shared__ float ao_s[NC*NL];      // [e][r]
    __shared__ float bulk_s[32*65];    // [lr][m], rows of this half, padded
    __shared__ float red1[32*8], red2[32*8];
    __shared__ float mstat[32], istat[32];

    const int t    = threadIdx.x;
    const int w    = t >> 6;
    const int l    = t & 63;
    const int bx   = blockIdx.x;
    const int b    = bx >> 3;
    const int s    = (bx >> 1) & 3;
    const int half = bx & 1;

    // stage this half's 32 bulk rows (8.1 KB), padded
    for (int idx = t; idx < 32*NL; idx += 256){
        int lr = idx >> 6, m = idx & 63;
        bulk_s[lr*65 + m] = bulk[b*NL*NL + (half*32 + lr)*NL + m];
    }

    fp sigp = (s == 0) ? ctcf : (s == 1) ? hac : (s == 2) ? me1 : me3;
    const float sig = sigp[b*NL + l];

    // ---- phase 1: embed + LN + QKV slice for row l ----
    float x[NC];
    float mean = 0.f;
#pragma unroll
    for (int c = 0; c < NC; c++){
        x[c] = sig * we_w[c] + we_b[c] + pos[l*NC + c];
        mean += x[c];
    }
    mean *= (1.f/NC);
    float var = 0.f;
#pragma unroll
    for (int c = 0; c < NC; c++){ float d = x[c] - mean; var += d*d; }
    var *= (1.f/NC);
    float inv = rsqrtf(var + 1e-5f);
#pragma unroll
    for (int c = 0; c < NC; c++) x[c] = (x[c] - mean)*inv*mn_g[c] + mn_b[c];

#pragma unroll
    for (int e8 = 0; e8 < ND; e8++){
        int e = w*ND + e8;
        float aq = bq[e], ak = bk[e], av = bv[e];
#pragma unroll
        for (int c = 0; c < NC; c++){
            float xv = x[c];
            aq += xv * wq[e*NC + c];
            ak += xv * wk[e*NC + c];
            av += xv * wv[e*NC + c];
        }
        qs_s[e*NL + l] = aq;
        ks_s[e*NL + l] = ak;
        vs_s[e*NL + l] = av;
        xs_s[e*NL + l] = x[e];
    }
    __syncthreads();

    // ---- phase 2: attention, head w, 2 lanes per row ----
    const int rl  = l >> 1;            // local row 0..31
    const int r   = half*32 + rl;      // global row
    const int mh_ = l & 1;             // m-half
    const int m0  = mh_*32;

    float q8[ND];
#pragma unroll
    for (int d = 0; d < ND; d++) q8[d] = qs_s[(w*ND + d)*NL + r];

    const float rs8 = 0.35355339059327373f;
    const float cw = conv_w[w], cb = conv_b[w];
    float srow[32];
    float mx = -1e30f;
    for (int mi = 0; mi < 32; mi++){
        int m = m0 + mi;
        float dot = 0.f;
#pragma unroll
        for (int d = 0; d < ND; d++)
            dot += q8[d] * ks_s[(w*ND + d)*NL + m];
        float v = dot*rs8 + bulk_s[rl*65 + m]*cw + cb;
        srow[mi] = v;
        mx = fmaxf(mx, v);
    }
    mx = fmaxf(mx, __shfl_xor(mx, 1));
    float sm = 0.f;
    for (int mi = 0; mi < 32; mi++){ srow[mi] = __expf(srow[mi] - mx); sm += srow[mi]; }
    sm += __shfl_xor(sm, 1);
    float is = 1.f / sm;

    float o[ND];
#pragma unroll
    for (int d = 0; d < ND; d++) o[d] = 0.f;
    for (int mi = 0; mi < 32; mi++){
        float a = srow[mi] * is;
#pragma unroll
        for (int d = 0; d < ND; d++)
            o[d] += a * vs_s[(w*ND + d)*NL + m0 + mi];
    }
#pragma unroll
    for (int d = 0; d < ND; d++) o[d] += __shfl_xor(o[d], 1);

    // gate: 4 channels per lane (c8 = mh_*4 + k)
#pragma unroll
    for (int k = 0; k < 4; k++){
        int c8 = mh_*4 + k;
        float g = gate_b[w*ND + c8];
#pragma unroll
        for (int d = 0; d < ND; d++) g += gate_w[(w*ND + c8)*ND + d] * o[d];
        ao_s[(w*ND + c8)*NL + r] = o[c8] * (1.f/(1.f + __expf(-g)));
    }
    __syncthreads();

    // ---- phase 3: out-proj (4 channels/thread) + residual + LN ----
    const int r3  = t & 31;            // local row
    const int rg  = half*32 + r3;      // global row
    const int cg  = t >> 5;            // channel group 0..7
    float vals[4];
    float psum = 0.f, psq = 0.f;
#pragma unroll
    for (int k = 0; k < 4; k++){
        int c = cg*4 + k;
        float a = bo[c];
#pragma unroll
        for (int e = 0; e < NC; e++) a += ao_s[e*NL + rg] * wo[c*NC + e];
        float val = xs_s[c*NL + rg] + a;
        vals[k] = val; psum += val; psq += val*val;
    }
    red1[r3*8 + cg] = psum;
    red2[r3*8 + cg] = psq;
    __syncthreads();
    if (t < 32){
        float sum = 0.f, ssq = 0.f;
#pragma unroll
        for (int g = 0; g < 8; g++){ sum += red1[t*8 + g]; ssq += red2[t*8 + g]; }
        float mn = sum * (1.f/NC);
        float vr = ssq * (1.f/NC) - mn*mn;
        mstat[t] = mn;
        istat[t] = rsqrtf(vr + 1e-5f);
    }
    __syncthreads();
    {
        float mn = mstat[r3], iv = istat[r3];
#pragma unroll
        for (int k = 0; k < 4; k++){
            int c = cg*4 + k;
            xpostT[((b*NS + s)*NC + c)*NL + rg] = (vals[k] - mn)*iv*an_g[c] + an_b[c];
        }
    }
}

// ---------------------------------------------------------------------------
// K23 v2 (unchanged from R11): block=(b,it) -> 512 blocks, 256 threads,
// 48 KB LDS. pp_w staged to LDS in two 32 KB passes; mhat cooperative.
// ---------------------------------------------------------------------------
__global__ __launch_bounds__(256) void k23_pair(
    const float* __restrict__ xpostT, fp pp_w,
    fp pp_b, fp ada_g, fp ada_b, fp ada_alpha,
    float* __restrict__ out)
{
    __shared__ float ppws[8*NC*NC];   // 8192 floats, 32 KB (per pass)
    __shared__ float mh[NC*NL];       // 2048 floats
    __shared__ float u[NCP*4*NC];     // 2048 floats ([0..63] = invn early)

    const int b  = blockIdx.x >> 4;
    const int it = blockIdx.x & 15;
    const int t  = threadIdx.x;
    const int w  = t >> 6;
    const int j  = t & 63;

    const float* xb = xpostT + b*NS*NC*NL;
#pragma unroll
    for (int k = 0; k < 8; k++){
        int cj = k*256 + t;
        float v = xb[cj];
        v = fmaxf(v, xb[NC*NL + cj]);
        v = fmaxf(v, xb[2*NC*NL + cj]);
        v = fmaxf(v, xb[3*NC*NL + cj]);
        mh[cj] = v;
    }
    __syncthreads();

    if (t < NL){
        float sq = 0.f;
#pragma unroll
        for (int c = 0; c < NC; c++){ float v = mh[c*NL + t]; sq += v*v; }
        u[t] = 1.f / fmaxf(sqrtf(sq), 1e-3f);
    }
    {
        const float4* src = (const float4*)(pp_w);
        float4* dst = (float4*)ppws;
#pragma unroll
        for (int k = 0; k < 8; k++) dst[k*256 + t] = src[k*256 + t];
    }
    __syncthreads();

#pragma unroll
    for (int k = 0; k < 8; k++){
        int cj = k*256 + t;
        mh[cj] *= u[cj & 63];
    }
    __syncthreads();

    float md[NC];
#pragma unroll
    for (int c = 0; c < NC; c++) md[c] = mh[c*NL + j];

#pragma unroll
    for (int loop = 0; loop < 4; loop++){
        int idx = loop*256 + t;
        int d  = idx & 31;
        int ip = (idx >> 5) & 3;
        int pl = idx >> 7;
        int i  = it*4 + ip;
        float acc = 0.f;
#pragma unroll
        for (int c = 0; c < NC; c++)
            acc += mh[c*NL + i] * ppws[pl*1024 + c*32 + d];
        u[pl*128 + ip*32 + d] = acc;
    }
    __syncthreads();

    {
        const float4* src = (const float4*)(pp_w + 8*NC*NC);
        float4* dst = (float4*)ppws;
#pragma unroll
        for (int k = 0; k < 8; k++) dst[k*256 + t] = src[k*256 + t];
    }
    __syncthreads();

#pragma unroll
    for (int loop = 0; loop < 4; loop++){
        int idx = loop*256 + t;
        int d  = idx & 31;
        int ip = (idx >> 5) & 3;
        int pl = idx >> 7;
        int i  = it*4 + ip;
        float acc = 0.f;
#pragma unroll
        for (int c = 0; c < NC; c++)
            acc += mh[c*NL + i] * ppws[pl*1024 + c*32 + d];
        u[(8 + pl)*128 + ip*32 + d] = acc;
    }
    __syncthreads();

    float f[NCP];
#pragma unroll 1
    for (int p = 0; p < NCP; p++){
        float a = 0.f;
#pragma unroll
        for (int d = 0; d < NC; d++)
            a += u[p*128 + w*32 + d] * md[d];
        f[p] = a;
    }

    const float alpha = ada_alpha[0];
    float fsum = 0.f, fsq = 0.f;
#pragma unroll
    for (int p = 0; p < NCP; p++){
        float v = f[p] + pp_b[p];
        f[p] = v; fsum += v; fsq += v*v;
    }
    float fmean = fsum * (1.f/NCP);
    float fvar  = fsq * (1.f/NCP) - fmean*fmean;
    float finv  = rsqrtf(fvar + 1e-5f);
    const int i = it*4 + w;
#pragma unroll
    for (int p = 0; p < NCP; p++){
        float v = f[p] + alpha * ((f[p] - fmean)*finv*ada_g[p] + ada_b[p]);
        out[((b*NCP + p)*NL + i)*NL + j] = v / (1.f + __expf(-v));
    }
}

extern "C" void kernel_launch(void* const* d_in, const int* in_sizes, int n_in,
                              void* d_out, int out_size, void* d_ws, size_t ws_size,
                              hipStream_t stream)
{
    float* xpostT = (float*)d_ws;                    // 32*4*32*64 = 262144 f32

    k1_attn<<<NB*NS*2, 256, 0, stream>>>(
        (fp)d_in[0], (fp)d_in[1], (fp)d_in[2], (fp)d_in[3], (fp)d_in[4],
        (fp)d_in[5], (fp)d_in[6], (fp)d_in[7], (fp)d_in[8], (fp)d_in[9],
        (fp)d_in[10], (fp)d_in[11], (fp)d_in[12], (fp)d_in[13], (fp)d_in[14], (fp)d_in[15],
        (fp)d_in[16], (fp)d_in[17], (fp)d_in[18], (fp)d_in[19],
        (fp)d_in[20], (fp)d_in[21], (fp)d_in[22], (fp)d_in[23], xpostT);

    k23_pair<<<NB*16, 256, 0, stream>>>(
        xpostT, (fp)d_in[24], (fp)d_in[25], (fp)d_in[26], (fp)d_in[27], (fp)d_in[28],
        (float*)d_out);
}